// Round 8
// baseline (536.120 us; speedup 1.0000x reference)
//
#include <hip/hip_runtime.h>
#include <hip/hip_fp16.h>

#define D_FEAT 128
#define N_LAYERS 4
#define HB 256            // histogram/bin blocks (slice mapping shared; multiple of 4)
#define ECAP 6080         // staged edge-index capacity (24320 B; +Atile+ccnt = 40960 B)
#define CHSHIFT 14        // 16384 rows x 256 B = 4 MB h16 chunk == one XCD's L2

typedef _Float16 f16x8 __attribute__((ext_vector_type(8)));
typedef float f32x4 __attribute__((ext_vector_type(4)));

// ---------- single-pass LDS packed-byte degree histograms + per-edge rank ----------
// Block b histograms its edge slice for BOTH src and dst (byte-packed, 4 nodes/word).
// 1024 threads/block: HB=256 blocks is grid-limited (1 block/CU), wider blocks are
// the occupancy lever. R5/R7 lesson: do NOT replace the partialA writeback with
// global atomics — both attempts regressed ~15-30 us.

__global__ __launch_bounds__(1024) void hist_kernel(
        const int* __restrict__ src, const int* __restrict__ dst,
        unsigned* __restrict__ partialA, unsigned* __restrict__ partialB,
        unsigned char* __restrict__ rank, int E, int W4) {
    extern __shared__ unsigned lds[];
    unsigned* hs = lds;
    unsigned* hd = lds + W4;
    int b = blockIdx.x;
    int chunk = (E + HB - 1) / HB;
    int e0 = b * chunk;
    int e1 = min(e0 + chunk, E);
    for (int w = threadIdx.x; w < W4; w += 1024) { hs[w] = 0; hd[w] = 0; }
    __syncthreads();
    for (int e = e0 + threadIdx.x; e < e1; e += 1024) {
        int s = src[e];
        int d = dst[e];
        atomicAdd(&hs[s >> 2], 1u << ((s & 3) * 8));
        int sh = (d & 3) * 8;
        unsigned old = atomicAdd(&hd[d >> 2], 1u << sh);
        rank[e] = (unsigned char)((old >> sh) & 0xffu);
    }
    __syncthreads();
    for (int w = threadIdx.x; w < W4; w += 1024) {
        partialA[(size_t)b * W4 + w] = hs[w];
        partialB[(size_t)b * W4 + w] = hd[w];
    }
}

// Coalesced sub-split cumscan; emits norms + per-256-node in-degree block sums.
__global__ __launch_bounds__(256) void cumscan_kernel(
        const unsigned* __restrict__ partialA,
        unsigned* __restrict__ partialB,
        int W4, int N,
        float* __restrict__ norm_src, float* __restrict__ norm_dst,
        int* __restrict__ deg_in, int* __restrict__ partials) {
    __shared__ unsigned sumA[4][64];
    __shared__ unsigned sumB[4][64];
    int s = threadIdx.x >> 6;            // sub / wave id, 0..3
    int wl = threadIdx.x & 63;
    int w = blockIdx.x * 64 + wl;
    bool ok = (w < W4);
    int b0 = s * (HB / 4);

    unsigned sa = 0, sb = 0;
    if (ok) {
        #pragma unroll 8
        for (int i = 0; i < HB / 4; ++i)
            sa += partialA[(size_t)(b0 + i) * W4 + w];
        #pragma unroll 8
        for (int i = 0; i < HB / 4; ++i)
            sb += partialB[(size_t)(b0 + i) * W4 + w];
    }
    sumA[s][wl] = sa;
    sumB[s][wl] = sb;
    __syncthreads();

    unsigned carry = 0;
    #pragma unroll
    for (int t = 0; t < 3; ++t)
        if (t < s) carry += sumB[t][wl];

    if (ok) {
        unsigned run = carry;
        #pragma unroll 8
        for (int i = 0; i < HB / 4; ++i) {
            size_t idx = (size_t)(b0 + i) * W4 + w;
            unsigned c = partialB[idx];
            partialB[idx] = run;
            run += c;
        }
    }

    if (s == 0) {
        int btot = 0;
        if (ok) {
            unsigned ta = sumA[0][wl] + sumA[1][wl] + sumA[2][wl] + sumA[3][wl];
            unsigned tb = sumB[0][wl] + sumB[1][wl] + sumB[2][wl] + sumB[3][wl];
            #pragma unroll
            for (int j = 0; j < 4; ++j) {
                int n = w * 4 + j;
                if (n < N) {
                    int da = (int)((ta >> (8 * j)) & 0xffu);
                    int db = (int)((tb >> (8 * j)) & 0xffu);
                    norm_src[n] = 1.0f / sqrtf((float)max(da, 1));
                    norm_dst[n] = 1.0f / sqrtf((float)max(db, 1));
                    deg_in[n] = db;
                    btot += db;
                }
            }
        }
        #pragma unroll
        for (int off = 32; off > 0; off >>= 1)
            btot += __shfl_down(btot, off, 64);
        if (wl == 0) partials[blockIdx.x] = btot;
    }
}

// Atomic-free, LDS-free binning: pos = row_ptr[d] + cross-block prefix + recorded rank.
__global__ __launch_bounds__(1024) void bin2_kernel(
        const int* __restrict__ src, const int* __restrict__ dst,
        const unsigned char* __restrict__ rank,
        const int* __restrict__ row_ptr, const unsigned* __restrict__ cumB,
        int* __restrict__ edge_src, int E, int W4) {
    int b = blockIdx.x;
    int chunk = (E + HB - 1) / HB;
    int e0 = b * chunk;
    int e1 = min(e0 + chunk, E);
    for (int e = e0 + threadIdx.x; e < e1; e += 1024) {
        int s = src[e];
        int d = dst[e];
        int sh = (d & 3) * 8;
        int base = (int)((cumB[(size_t)b * W4 + (d >> 2)] >> sh) & 0xffu);
        edge_src[row_ptr[d] + base + (int)rank[e]] = s;
    }
}

// ---------- legacy fallback (only if node range too big for LDS histogram) ----------

__global__ void degree_kernel(const int* __restrict__ src, const int* __restrict__ dst,
                              int* __restrict__ deg_out, int* __restrict__ deg_in, int E) {
    int e = blockIdx.x * blockDim.x + threadIdx.x;
    if (e < E) {
        atomicAdd(&deg_out[src[e]], 1);
        atomicAdd(&deg_in[dst[e]], 1);
    }
}

__global__ void norm_kernel(const int* __restrict__ deg_out, const int* __restrict__ deg_in,
                            float* __restrict__ norm_src, float* __restrict__ norm_dst, int N) {
    int i = blockIdx.x * blockDim.x + threadIdx.x;
    if (i < N) {
        norm_src[i] = 1.0f / sqrtf((float)max(deg_out[i], 1));
        norm_dst[i] = 1.0f / sqrtf((float)max(deg_in[i], 1));
    }
}

__global__ void bin_kernel(const int* __restrict__ src, const int* __restrict__ dst,
                           int* __restrict__ cursor, int* __restrict__ edge_src, int E) {
    int e = blockIdx.x * blockDim.x + threadIdx.x;
    if (e < E) {
        int p = atomicAdd(&cursor[dst[e]], 1);
        edge_src[p] = src[e];
    }
}

__global__ void scan_local_kernel(const int* __restrict__ deg, int* __restrict__ row_ptr,
                                  int* __restrict__ partials, int N) {
    __shared__ int wsum[4];
    int i = blockIdx.x * 256 + threadIdx.x;
    int lane = threadIdx.x & 63;
    int wid = threadIdx.x >> 6;
    int v = (i < N) ? deg[i] : 0;
    int x = v;
    #pragma unroll
    for (int off = 1; off < 64; off <<= 1) {
        int t = __shfl_up(x, off, 64);
        if (lane >= off) x += t;
    }
    if (lane == 63) wsum[wid] = x;
    __syncthreads();
    if (threadIdx.x == 0) {
        int s = 0;
        #pragma unroll
        for (int j = 0; j < 4; ++j) { int t = wsum[j]; wsum[j] = s; s += t; }
        partials[blockIdx.x] = s;
    }
    __syncthreads();
    int excl = wsum[wid] + x - v;
    if (i < N) row_ptr[i] = excl;
}

// ---------- hierarchical exclusive scan (shared) ----------

__global__ void scan_partials_kernel(int* __restrict__ partials, int P,
                                     int* __restrict__ row_ptr, int N, int E) {
    __shared__ int wsum[4];
    int lane = threadIdx.x & 63;
    int wid = threadIdx.x >> 6;
    int v = (threadIdx.x < P) ? partials[threadIdx.x] : 0;
    int x = v;
    #pragma unroll
    for (int off = 1; off < 64; off <<= 1) {
        int t = __shfl_up(x, off, 64);
        if (lane >= off) x += t;
    }
    if (lane == 63) wsum[wid] = x;
    __syncthreads();
    if (threadIdx.x == 0) {
        int s = 0;
        #pragma unroll
        for (int j = 0; j < 4; ++j) { int t = wsum[j]; wsum[j] = s; s += t; }
    }
    __syncthreads();
    if (threadIdx.x < P) partials[threadIdx.x] = wsum[wid] + x - v;
    if (threadIdx.x == 0) row_ptr[N] = E;
}

// Local exclusive scan + scanned-partial add in one pass (fast path).
__global__ void scan_final_kernel(const int* __restrict__ deg,
                                  const int* __restrict__ partials,
                                  int* __restrict__ row_ptr, int* __restrict__ cursor, int N) {
    __shared__ int wsum[4];
    int i = blockIdx.x * 256 + threadIdx.x;
    int lane = threadIdx.x & 63;
    int wid = threadIdx.x >> 6;
    int v = (i < N) ? deg[i] : 0;
    int x = v;
    #pragma unroll
    for (int off = 1; off < 64; off <<= 1) {
        int t = __shfl_up(x, off, 64);
        if (lane >= off) x += t;
    }
    if (lane == 63) wsum[wid] = x;
    __syncthreads();
    if (threadIdx.x == 0) {
        int s = 0;
        #pragma unroll
        for (int j = 0; j < 4; ++j) { int t = wsum[j]; wsum[j] = s; s += t; }
    }
    __syncthreads();
    if (i < N) {
        int excl = wsum[wid] + x - v + partials[blockIdx.x];
        row_ptr[i] = excl;
        cursor[i] = excl;
    }
}

__global__ void scan_add_kernel(int* __restrict__ row_ptr, int* __restrict__ cursor,
                                const int* __restrict__ partials, int N) {
    int i = blockIdx.x * 256 + threadIdx.x;
    if (i < N) {
        int v = row_ptr[i] + partials[blockIdx.x];
        row_ptr[i] = v;
        cursor[i] = v;
    }
}

// ---------- merged converts: h16 = feat*norm_src, Wf = fragment-ordered fp16 W ----------

__global__ void conv_kernel(const float* __restrict__ feat, const float* __restrict__ norm_src,
                            __half* __restrict__ h16,
                            const float* __restrict__ W, _Float16* __restrict__ Wf,
                            int n4, int wtotal) {
    int i = blockIdx.x * 256 + threadIdx.x;
    if (i < n4) {
        float ns = norm_src[i >> 5];
        float4 v = ((const float4*)feat)[i];
        __half2 a = __floats2half2_rn(v.x * ns, v.y * ns);
        __half2 b = __floats2half2_rn(v.z * ns, v.w * ns);
        uint2 o;
        o.x = *(unsigned*)&a;
        o.y = *(unsigned*)&b;
        ((uint2*)h16)[i] = o;
    } else {
        int idx = i - n4;
        if (idx < wtotal) {
            int l = idx >> 14;
            int k = (idx >> 7) & 127;
            int n = idx & 127;
            float v = W[idx];
            int frag = (k >> 5) * 8 + (n >> 4);
            int lane = ((k >> 3) & 3) * 16 + (n & 15);
            Wf[(size_t)l * 16384 + frag * 512 + lane * 8 + (k & 7)] = (_Float16)v;
        }
    }
}

// ---------- fused per-layer: CSR aggregation into LDS + MFMA GEMM ----------
// NEW (this round): source-chunked gather passes. h16 (12.8 MB) >> 4 MB per-XCD
// L2 -> random gathers were ~31% L2-hit, effective ~6.3 TB/s. Group each row's
// staged edge indices by src chunk (16384 rows = 4 MB = one L2), then all blocks
// sweep chunks in the same order: during pass c every XCD's L2 holds chunk c.
// Grouping = per-row 4-bucket counting sort in LDS (scratch = Atile space, which
// is unused until after the gathers). Rows > 64 edges (or nchunk outside 2..4)
// stay ungrouped and gather fully in pass 0 — correctness never depends on it.

template <class F>
__device__ __forceinline__ void gather_node(const uint4* __restrict__ hv, int l16,
                                            int e0, int e1, F edge_at, float acc[8]) {
    int e = e0;
    for (; e + 8 <= e1; e += 8) {
        int s[8];
        uint4 v[8];
        #pragma unroll
        for (int q = 0; q < 8; ++q) s[q] = edge_at(e + q);
        #pragma unroll
        for (int q = 0; q < 8; ++q) v[q] = hv[(size_t)s[q] * 16 + l16];
        #pragma unroll
        for (int q = 0; q < 8; ++q) {
            #pragma unroll
            for (int p = 0; p < 4; ++p) {
                unsigned u = (&v[q].x)[p];
                float2 f = __half22float2(*(__half2*)&u);
                acc[2 * p] += f.x;
                acc[2 * p + 1] += f.y;
            }
        }
    }
    for (; e + 4 <= e1; e += 4) {
        int s[4];
        uint4 v[4];
        #pragma unroll
        for (int q = 0; q < 4; ++q) s[q] = edge_at(e + q);
        #pragma unroll
        for (int q = 0; q < 4; ++q) v[q] = hv[(size_t)s[q] * 16 + l16];
        #pragma unroll
        for (int q = 0; q < 4; ++q) {
            #pragma unroll
            for (int p = 0; p < 4; ++p) {
                unsigned u = (&v[q].x)[p];
                float2 f = __half22float2(*(__half2*)&u);
                acc[2 * p] += f.x;
                acc[2 * p + 1] += f.y;
            }
        }
    }
    for (; e < e1; ++e) {
        int s = edge_at(e);
        uint4 v = hv[(size_t)s * 16 + l16];
        #pragma unroll
        for (int p = 0; p < 4; ++p) {
            unsigned u = (&v.x)[p];
            float2 f = __half22float2(*(__half2*)&u);
            acc[2 * p] += f.x;
            acc[2 * p + 1] += f.y;
        }
    }
}

__global__ __launch_bounds__(256) void agg_gemm_kernel(
        const __half* __restrict__ h16, const int* __restrict__ row_ptr,
        const int* __restrict__ edge_src, const float* __restrict__ norm_dst,
        const _Float16* __restrict__ Wf, const float* __restrict__ bias,
        const float* __restrict__ norm_src,
        __half* __restrict__ out16, float* __restrict__ out32, int N) {
    __shared__ f16x8 Atile[64 * 16];     // [row][chunk^(row&7)]; pre-gather: sort scratch
    __shared__ int eidx[ECAP];           // staged edge_src slice for this block
    __shared__ unsigned ccnt[64];        // packed per-row chunk counts (4 bytes/row)

    int tid = threadIdx.x;
    int l16 = tid & 15;                  // 16-B chunk id within the 256-B row
    int nodeofs = tid >> 4;              // 0..15
    int base = blockIdx.x * 64;
    const uint4* hv = (const uint4*)h16; // row = 16 x uint4

    int nend = min(base + 64, N);
    int eb0 = row_ptr[base];
    int ecnt = row_ptr[nend] - eb0;
    bool staged = (ecnt <= ECAP);
    if (staged) {
        for (int i = tid; i < ecnt; i += 256) eidx[i] = edge_src[eb0 + i];
    }
    __syncthreads();

    int nchunk = (N + (1 << CHSHIFT) - 1) >> CHSHIFT;
    bool grouped = staged && nchunk >= 2 && nchunk <= 4;

    if (grouped) {
        if (l16 == 0) {                  // 16 worker threads, 4 rows each
            int* scratch = (int*)Atile;  // 4096 ints = 64 rows x 64
            #pragma unroll 1
            for (int j = 0; j < 4; ++j) {
                int nl = nodeofs + j * 16;
                int node = base + nl;
                unsigned cntw = 0;
                if (node < N) {
                    int e0 = row_ptr[node] - eb0;
                    int len = row_ptr[node + 1] - eb0 - e0;
                    if (len <= 64) {
                        int c0 = 0, c1 = 0, c2 = 0, c3 = 0;
                        int* sr = scratch + nl * 64;
                        for (int e = 0; e < len; ++e) {
                            int s = eidx[e0 + e];
                            sr[e] = s;
                            int c = s >> CHSHIFT;
                            c0 += (c == 0); c1 += (c == 1);
                            c2 += (c == 2); c3 += (c == 3);
                        }
                        int o0 = 0, o1 = c0, o2 = c0 + c1, o3 = c0 + c1 + c2;
                        for (int e = 0; e < len; ++e) {
                            int s = sr[e];
                            int c = s >> CHSHIFT;
                            int pos = (c == 0) ? o0++ : (c == 1) ? o1++
                                    : (c == 2) ? o2++ : o3++;
                            eidx[e0 + pos] = s;
                        }
                        cntw = (unsigned)c0 | ((unsigned)c1 << 8)
                             | ((unsigned)c2 << 16) | ((unsigned)c3 << 24);
                    } else {
                        cntw = 0x80000000u;   // long row: ungrouped, all in pass 0
                    }
                }
                ccnt[nl] = cntw;
            }
        }
        __syncthreads();

        float acc[4][8] = {};
        int p[4], qlen[4];
        unsigned cw[4];
        #pragma unroll
        for (int j = 0; j < 4; ++j) {
            int nl = nodeofs + j * 16;
            int node = base + nl;
            p[j] = (node < N) ? row_ptr[node] - eb0 : 0;
            qlen[j] = (node < N) ? row_ptr[node + 1] - eb0 - p[j] : 0;
            cw[j] = ccnt[nl];
        }
        #pragma unroll 1
        for (int c = 0; c < 4; ++c) {
            #pragma unroll
            for (int j = 0; j < 4; ++j) {
                int run;
                if (cw[j] & 0x80000000u) run = (c == 0) ? qlen[j] : 0;
                else run = (int)((cw[j] >> (8 * c)) & 0xffu);
                if (run > 0) {
                    const int* ep = eidx;
                    gather_node(hv, l16, p[j], p[j] + run,
                                [&](int e) { return ep[e]; }, acc[j]);
                    p[j] += run;
                }
            }
        }
        #pragma unroll
        for (int j = 0; j < 4; ++j) {
            int nl = nodeofs + j * 16;
            int node = base + nl;
            float nd = (node < N) ? norm_dst[node] : 0.0f;
            f16x8 o;
            #pragma unroll
            for (int pq = 0; pq < 8; ++pq) o[pq] = (_Float16)(acc[j][pq] * nd);
            Atile[nl * 16 + (l16 ^ (nl & 7))] = o;
        }
    } else {
        #pragma unroll 1
        for (int j = 0; j < 4; ++j) {
            int nl = nodeofs + j * 16;
            int node = base + nl;
            float acc[8] = {};
            if (node < N) {
                int e0 = row_ptr[node];
                int e1 = row_ptr[node + 1];
                if (staged) {
                    const int* ep = eidx;
                    gather_node(hv, l16, e0 - eb0, e1 - eb0,
                                [&](int e) { return ep[e]; }, acc);
                } else {
                    gather_node(hv, l16, e0, e1,
                                [&](int e) { return edge_src[e]; }, acc);
                }
                float nd = norm_dst[node];
                #pragma unroll
                for (int pq = 0; pq < 8; ++pq) acc[pq] *= nd;
            }
            f16x8 o;
            #pragma unroll
            for (int pq = 0; pq < 8; ++pq) o[pq] = (_Float16)acc[pq];
            Atile[nl * 16 + (l16 ^ (nl & 7))] = o;
        }
    }
    __syncthreads();

    // ---- GEMM phase: 4 waves, each 16 rows x 128 cols ----
    int lane = tid & 63;
    int wave = tid >> 6;
    int m = lane & 15;
    int quad = lane >> 4;
    int rb = wave * 16;

    f32x4 acc[8] = {};
    #pragma unroll
    for (int kb = 0; kb < 4; ++kb) {
        int rl = rb + m;
        f16x8 a = Atile[rl * 16 + ((kb * 4 + quad) ^ (rl & 7))];
        const f16x8* wf = (const f16x8*)(Wf + (size_t)kb * 4096);
        #pragma unroll
        for (int nb = 0; nb < 8; ++nb) {
            f16x8 bfrag = wf[nb * 64 + lane];
            acc[nb] = __builtin_amdgcn_mfma_f32_16x16x32_f16(a, bfrag, acc[nb], 0, 0, 0);
        }
    }

    float bv[8];
    #pragma unroll
    for (int nb = 0; nb < 8; ++nb) bv[nb] = bias[nb * 16 + m];

    #pragma unroll
    for (int r = 0; r < 4; ++r) {
        int row = base + rb + quad * 4 + r;
        if (row < N) {
            if (out32 != nullptr) {
                #pragma unroll
                for (int nb = 0; nb < 8; ++nb)
                    out32[(size_t)row * 128 + nb * 16 + m] = acc[nb][r] + bv[nb];
            } else {
                float ns = norm_src[row];
                #pragma unroll
                for (int nb = 0; nb < 8; ++nb)
                    out16[(size_t)row * 128 + nb * 16 + m] =
                        __float2half((acc[nb][r] + bv[nb]) * ns);
            }
        }
    }
}

// ---------- launch ----------

extern "C" void kernel_launch(void* const* d_in, const int* in_sizes, int n_in,
                              void* d_out, int out_size, void* d_ws, size_t ws_size,
                              hipStream_t stream) {
    const float* feat = (const float*)d_in[0];
    const float* W    = (const float*)d_in[1];
    const float* b    = (const float*)d_in[2];
    const int*   src  = (const int*)d_in[3];
    const int*   dst  = (const int*)d_in[4];
    const int D = D_FEAT;
    const int N = in_sizes[0] / D;
    const int E = in_sizes[3];
    const int P = (N + 255) / 256;
    const int W4 = (N + 3) / 4;

    char* ws = (char*)d_ws;
    int* deg_in   = (int*)ws;                 // N
    int* row_ptr  = deg_in + N;               // N+1
    int* partials = row_ptr + (N + 1);        // P
    int* cursor   = partials + P;             // N (fallback only)
    int* edge_src = cursor + N;               // E
    float* norm_src_p = (float*)(edge_src + E);   // N
    float* norm_dst_p = norm_src_p + N;           // N
    unsigned char* rank = (unsigned char*)(norm_dst_p + N);  // E bytes
    unsigned* partialA = (unsigned*)(((size_t)(rank + E) + 255) & ~(size_t)255); // HB*W4
    unsigned* partialB = partialA + (size_t)HB * W4;                              // HB*W4
    size_t off = (size_t)((char*)(partialB + (size_t)HB * W4) - ws);
    off = (off + 255) & ~(size_t)255;
    __half* h_a = (__half*)(ws + off);            // N*128
    __half* h_b = h_a + (size_t)N * D;            // N*128
    _Float16* Wf = (_Float16*)(h_b + (size_t)N * D);  // 4*128*128

    bool fast = (2 * (size_t)W4 * 4 <= 160 * 1024 - 2048);
    if (fast) {
        hist_kernel<<<HB, 1024, 2 * (size_t)W4 * 4, stream>>>(
            src, dst, partialA, partialB, rank, E, W4);
        cumscan_kernel<<<(W4 + 63) / 64, 256, 0, stream>>>(
            partialA, partialB, W4, N, norm_src_p, norm_dst_p, deg_in, partials);
        scan_partials_kernel<<<1, 256, 0, stream>>>(partials, P, row_ptr, N, E);
        scan_final_kernel<<<P, 256, 0, stream>>>(deg_in, partials, row_ptr, cursor, N);
        bin2_kernel<<<HB, 1024, 0, stream>>>(src, dst, rank, row_ptr, partialB,
                                             edge_src, E, W4);
    } else {
        int* deg_out = (int*)partialA;
        hipMemsetAsync(deg_out, 0, sizeof(int) * (size_t)N, stream);
        hipMemsetAsync(deg_in, 0, sizeof(int) * (size_t)N, stream);
        degree_kernel<<<(E + 255) / 256, 256, 0, stream>>>(src, dst, deg_out, deg_in, E);
        norm_kernel<<<(N + 255) / 256, 256, 0, stream>>>(deg_out, deg_in, norm_src_p, norm_dst_p, N);
        scan_local_kernel<<<P, 256, 0, stream>>>(deg_in, row_ptr, partials, N);
        scan_partials_kernel<<<1, 256, 0, stream>>>(partials, P, row_ptr, N, E);
        scan_add_kernel<<<P, 256, 0, stream>>>(row_ptr, cursor, partials, N);
        bin_kernel<<<(E + 255) / 256, 256, 0, stream>>>(src, dst, cursor, edge_src, E);
    }
    int n4 = N * 32;
    int wtotal = N_LAYERS * 16384;
    conv_kernel<<<(n4 + wtotal + 255) / 256, 256, 0, stream>>>(
        feat, norm_src_p, h_a, W, Wf, n4, wtotal);

    const __half* hin = h_a;
    __half* hout = h_b;
    for (int l = 0; l < N_LAYERS; ++l) {
        bool last = (l == N_LAYERS - 1);
        agg_gemm_kernel<<<(N + 63) / 64, 256, 0, stream>>>(
            hin, row_ptr, edge_src, norm_dst_p,
            Wf + (size_t)l * 16384, b + (size_t)l * D, norm_src_p,
            last ? nullptr : hout, last ? (float*)d_out : nullptr, N);
        const __half* t = hin; hin = hout; hout = (__half*)t;
    }
}

// Round 9
// 261.550 us; speedup vs baseline: 2.0498x; 2.0498x over previous
//
#include <hip/hip_runtime.h>
#include <hip/hip_fp16.h>

#define D_FEAT 128
#define N_LAYERS 4
#define HB 256            // histogram/bin blocks (slice mapping shared; multiple of 4)
#define ECAP 6144         // staged edge-index capacity per block (24 KB LDS)

typedef _Float16 f16x8 __attribute__((ext_vector_type(8)));
typedef float f32x4 __attribute__((ext_vector_type(4)));

// ---------- single-pass LDS packed-byte degree histograms + per-edge rank ----------
// Block b histograms its edge slice for BOTH src and dst (byte-packed, 4 nodes/word).
// 1024 threads/block: HB=256 blocks is grid-limited (1 block/CU); wider blocks are
// the occupancy lever. R5/R7 lesson: do NOT replace the partialA writeback with
// global atomics. R8 lesson: do NOT add in-kernel edge sorting for locality —
// serial sort + LDS bank conflicts cost 3x what the locality saved.

__global__ __launch_bounds__(1024) void hist_kernel(
        const int* __restrict__ src, const int* __restrict__ dst,
        unsigned* __restrict__ partialA, unsigned* __restrict__ partialB,
        unsigned char* __restrict__ rank, int E, int W4) {
    extern __shared__ unsigned lds[];
    unsigned* hs = lds;
    unsigned* hd = lds + W4;
    int b = blockIdx.x;
    int chunk = (E + HB - 1) / HB;
    int e0 = b * chunk;
    int e1 = min(e0 + chunk, E);
    for (int w = threadIdx.x; w < W4; w += 1024) { hs[w] = 0; hd[w] = 0; }
    __syncthreads();
    for (int e = e0 + threadIdx.x; e < e1; e += 1024) {
        int s = src[e];
        int d = dst[e];
        atomicAdd(&hs[s >> 2], 1u << ((s & 3) * 8));
        int sh = (d & 3) * 8;
        unsigned old = atomicAdd(&hd[d >> 2], 1u << sh);
        rank[e] = (unsigned char)((old >> sh) & 0xffu);
    }
    __syncthreads();
    for (int w = threadIdx.x; w < W4; w += 1024) {
        partialA[(size_t)b * W4 + w] = hs[w];
        partialB[(size_t)b * W4 + w] = hd[w];
    }
}

// Coalesced sub-split cumscan; emits norms + per-256-node in-degree block sums.
__global__ __launch_bounds__(256) void cumscan_kernel(
        const unsigned* __restrict__ partialA,
        unsigned* __restrict__ partialB,
        int W4, int N,
        float* __restrict__ norm_src, float* __restrict__ norm_dst,
        int* __restrict__ deg_in, int* __restrict__ partials) {
    __shared__ unsigned sumA[4][64];
    __shared__ unsigned sumB[4][64];
    int s = threadIdx.x >> 6;            // sub / wave id, 0..3
    int wl = threadIdx.x & 63;
    int w = blockIdx.x * 64 + wl;
    bool ok = (w < W4);
    int b0 = s * (HB / 4);

    unsigned sa = 0, sb = 0;
    if (ok) {
        #pragma unroll 8
        for (int i = 0; i < HB / 4; ++i)
            sa += partialA[(size_t)(b0 + i) * W4 + w];
        #pragma unroll 8
        for (int i = 0; i < HB / 4; ++i)
            sb += partialB[(size_t)(b0 + i) * W4 + w];
    }
    sumA[s][wl] = sa;
    sumB[s][wl] = sb;
    __syncthreads();

    unsigned carry = 0;
    #pragma unroll
    for (int t = 0; t < 3; ++t)
        if (t < s) carry += sumB[t][wl];

    if (ok) {
        unsigned run = carry;
        #pragma unroll 8
        for (int i = 0; i < HB / 4; ++i) {
            size_t idx = (size_t)(b0 + i) * W4 + w;
            unsigned c = partialB[idx];
            partialB[idx] = run;
            run += c;
        }
    }

    if (s == 0) {
        int btot = 0;
        if (ok) {
            unsigned ta = sumA[0][wl] + sumA[1][wl] + sumA[2][wl] + sumA[3][wl];
            unsigned tb = sumB[0][wl] + sumB[1][wl] + sumB[2][wl] + sumB[3][wl];
            #pragma unroll
            for (int j = 0; j < 4; ++j) {
                int n = w * 4 + j;
                if (n < N) {
                    int da = (int)((ta >> (8 * j)) & 0xffu);
                    int db = (int)((tb >> (8 * j)) & 0xffu);
                    norm_src[n] = 1.0f / sqrtf((float)max(da, 1));
                    norm_dst[n] = 1.0f / sqrtf((float)max(db, 1));
                    deg_in[n] = db;
                    btot += db;
                }
            }
        }
        #pragma unroll
        for (int off = 32; off > 0; off >>= 1)
            btot += __shfl_down(btot, off, 64);
        if (wl == 0) partials[blockIdx.x] = btot;
    }
}

// Atomic-free, LDS-free binning: pos = row_ptr[d] + cross-block prefix + recorded rank.
__global__ __launch_bounds__(1024) void bin2_kernel(
        const int* __restrict__ src, const int* __restrict__ dst,
        const unsigned char* __restrict__ rank,
        const int* __restrict__ row_ptr, const unsigned* __restrict__ cumB,
        int* __restrict__ edge_src, int E, int W4) {
    int b = blockIdx.x;
    int chunk = (E + HB - 1) / HB;
    int e0 = b * chunk;
    int e1 = min(e0 + chunk, E);
    for (int e = e0 + threadIdx.x; e < e1; e += 1024) {
        int s = src[e];
        int d = dst[e];
        int sh = (d & 3) * 8;
        int base = (int)((cumB[(size_t)b * W4 + (d >> 2)] >> sh) & 0xffu);
        edge_src[row_ptr[d] + base + (int)rank[e]] = s;
    }
}

// ---------- legacy fallback (only if node range too big for LDS histogram) ----------

__global__ void degree_kernel(const int* __restrict__ src, const int* __restrict__ dst,
                              int* __restrict__ deg_out, int* __restrict__ deg_in, int E) {
    int e = blockIdx.x * blockDim.x + threadIdx.x;
    if (e < E) {
        atomicAdd(&deg_out[src[e]], 1);
        atomicAdd(&deg_in[dst[e]], 1);
    }
}

__global__ void norm_kernel(const int* __restrict__ deg_out, const int* __restrict__ deg_in,
                            float* __restrict__ norm_src, float* __restrict__ norm_dst, int N) {
    int i = blockIdx.x * blockDim.x + threadIdx.x;
    if (i < N) {
        norm_src[i] = 1.0f / sqrtf((float)max(deg_out[i], 1));
        norm_dst[i] = 1.0f / sqrtf((float)max(deg_in[i], 1));
    }
}

__global__ void bin_kernel(const int* __restrict__ src, const int* __restrict__ dst,
                           int* __restrict__ cursor, int* __restrict__ edge_src, int E) {
    int e = blockIdx.x * blockDim.x + threadIdx.x;
    if (e < E) {
        int p = atomicAdd(&cursor[dst[e]], 1);
        edge_src[p] = src[e];
    }
}

__global__ void scan_local_kernel(const int* __restrict__ deg, int* __restrict__ row_ptr,
                                  int* __restrict__ partials, int N) {
    __shared__ int wsum[4];
    int i = blockIdx.x * 256 + threadIdx.x;
    int lane = threadIdx.x & 63;
    int wid = threadIdx.x >> 6;
    int v = (i < N) ? deg[i] : 0;
    int x = v;
    #pragma unroll
    for (int off = 1; off < 64; off <<= 1) {
        int t = __shfl_up(x, off, 64);
        if (lane >= off) x += t;
    }
    if (lane == 63) wsum[wid] = x;
    __syncthreads();
    if (threadIdx.x == 0) {
        int s = 0;
        #pragma unroll
        for (int j = 0; j < 4; ++j) { int t = wsum[j]; wsum[j] = s; s += t; }
        partials[blockIdx.x] = s;
    }
    __syncthreads();
    int excl = wsum[wid] + x - v;
    if (i < N) row_ptr[i] = excl;
}

// ---------- hierarchical exclusive scan (shared) ----------

__global__ void scan_partials_kernel(int* __restrict__ partials, int P,
                                     int* __restrict__ row_ptr, int N, int E) {
    __shared__ int wsum[4];
    int lane = threadIdx.x & 63;
    int wid = threadIdx.x >> 6;
    int v = (threadIdx.x < P) ? partials[threadIdx.x] : 0;
    int x = v;
    #pragma unroll
    for (int off = 1; off < 64; off <<= 1) {
        int t = __shfl_up(x, off, 64);
        if (lane >= off) x += t;
    }
    if (lane == 63) wsum[wid] = x;
    __syncthreads();
    if (threadIdx.x == 0) {
        int s = 0;
        #pragma unroll
        for (int j = 0; j < 4; ++j) { int t = wsum[j]; wsum[j] = s; s += t; }
    }
    __syncthreads();
    if (threadIdx.x < P) partials[threadIdx.x] = wsum[wid] + x - v;
    if (threadIdx.x == 0) row_ptr[N] = E;
}

// Local exclusive scan + scanned-partial add in one pass (fast path).
__global__ void scan_final_kernel(const int* __restrict__ deg,
                                  const int* __restrict__ partials,
                                  int* __restrict__ row_ptr, int* __restrict__ cursor, int N) {
    __shared__ int wsum[4];
    int i = blockIdx.x * 256 + threadIdx.x;
    int lane = threadIdx.x & 63;
    int wid = threadIdx.x >> 6;
    int v = (i < N) ? deg[i] : 0;
    int x = v;
    #pragma unroll
    for (int off = 1; off < 64; off <<= 1) {
        int t = __shfl_up(x, off, 64);
        if (lane >= off) x += t;
    }
    if (lane == 63) wsum[wid] = x;
    __syncthreads();
    if (threadIdx.x == 0) {
        int s = 0;
        #pragma unroll
        for (int j = 0; j < 4; ++j) { int t = wsum[j]; wsum[j] = s; s += t; }
    }
    __syncthreads();
    if (i < N) {
        int excl = wsum[wid] + x - v + partials[blockIdx.x];
        row_ptr[i] = excl;
        cursor[i] = excl;
    }
}

__global__ void scan_add_kernel(int* __restrict__ row_ptr, int* __restrict__ cursor,
                                const int* __restrict__ partials, int N) {
    int i = blockIdx.x * 256 + threadIdx.x;
    if (i < N) {
        int v = row_ptr[i] + partials[blockIdx.x];
        row_ptr[i] = v;
        cursor[i] = v;
    }
}

// ---------- merged converts: h16 = feat*norm_src, Wf = fragment-ordered fp16 W ----------

__global__ void conv_kernel(const float* __restrict__ feat, const float* __restrict__ norm_src,
                            __half* __restrict__ h16,
                            const float* __restrict__ W, _Float16* __restrict__ Wf,
                            int n4, int wtotal) {
    int i = blockIdx.x * 256 + threadIdx.x;
    if (i < n4) {
        float ns = norm_src[i >> 5];
        float4 v = ((const float4*)feat)[i];
        __half2 a = __floats2half2_rn(v.x * ns, v.y * ns);
        __half2 b = __floats2half2_rn(v.z * ns, v.w * ns);
        uint2 o;
        o.x = *(unsigned*)&a;
        o.y = *(unsigned*)&b;
        ((uint2*)h16)[i] = o;
    } else {
        int idx = i - n4;
        if (idx < wtotal) {
            int l = idx >> 14;
            int k = (idx >> 7) & 127;
            int n = idx & 127;
            float v = W[idx];
            int frag = (k >> 5) * 8 + (n >> 4);
            int lane = ((k >> 3) & 3) * 16 + (n & 15);
            Wf[(size_t)l * 16384 + frag * 512 + lane * 8 + (k & 7)] = (_Float16)v;
        }
    }
}

// ---------- fused per-layer: CSR aggregation into LDS + MFMA GEMM (R6 proven form) ----------

template <class F>
__device__ __forceinline__ void gather_node(const uint4* __restrict__ hv, int l16,
                                            int e0, int e1, F edge_at, float acc[8]) {
    int e = e0;
    for (; e + 8 <= e1; e += 8) {
        int s[8];
        uint4 v[8];
        #pragma unroll
        for (int q = 0; q < 8; ++q) s[q] = edge_at(e + q);
        #pragma unroll
        for (int q = 0; q < 8; ++q) v[q] = hv[(size_t)s[q] * 16 + l16];
        #pragma unroll
        for (int q = 0; q < 8; ++q) {
            #pragma unroll
            for (int p = 0; p < 4; ++p) {
                unsigned u = (&v[q].x)[p];
                float2 f = __half22float2(*(__half2*)&u);
                acc[2 * p] += f.x;
                acc[2 * p + 1] += f.y;
            }
        }
    }
    for (; e + 4 <= e1; e += 4) {
        int s[4];
        uint4 v[4];
        #pragma unroll
        for (int q = 0; q < 4; ++q) s[q] = edge_at(e + q);
        #pragma unroll
        for (int q = 0; q < 4; ++q) v[q] = hv[(size_t)s[q] * 16 + l16];
        #pragma unroll
        for (int q = 0; q < 4; ++q) {
            #pragma unroll
            for (int p = 0; p < 4; ++p) {
                unsigned u = (&v[q].x)[p];
                float2 f = __half22float2(*(__half2*)&u);
                acc[2 * p] += f.x;
                acc[2 * p + 1] += f.y;
            }
        }
    }
    for (; e < e1; ++e) {
        int s = edge_at(e);
        uint4 v = hv[(size_t)s * 16 + l16];
        #pragma unroll
        for (int p = 0; p < 4; ++p) {
            unsigned u = (&v.x)[p];
            float2 f = __half22float2(*(__half2*)&u);
            acc[2 * p] += f.x;
            acc[2 * p + 1] += f.y;
        }
    }
}

__global__ __launch_bounds__(256) void agg_gemm_kernel(
        const __half* __restrict__ h16, const int* __restrict__ row_ptr,
        const int* __restrict__ edge_src, const float* __restrict__ norm_dst,
        const _Float16* __restrict__ Wf, const float* __restrict__ bias,
        const float* __restrict__ norm_src,
        __half* __restrict__ out16, float* __restrict__ out32, int N) {
    __shared__ f16x8 Atile[64 * 16];     // [local_row][chunk ^ (row&7)]
    __shared__ int eidx[ECAP];           // staged edge_src slice for this block

    int tid = threadIdx.x;
    int l16 = tid & 15;                  // 16-B chunk id within the 256-B row
    int nodeofs = tid >> 4;              // 0..15
    int base = blockIdx.x * 64;
    const uint4* hv = (const uint4*)h16; // row = 16 x uint4

    int nend = min(base + 64, N);
    int eb0 = row_ptr[base];
    int ecnt = row_ptr[nend] - eb0;
    bool staged = (ecnt <= ECAP);
    if (staged) {
        for (int i = tid; i < ecnt; i += 256) eidx[i] = edge_src[eb0 + i];
    }
    __syncthreads();

    #pragma unroll 1
    for (int j = 0; j < 4; ++j) {
        int nl = nodeofs + j * 16;       // local row 0..63
        int node = base + nl;
        float acc[8] = {};
        if (node < N) {
            int e0 = row_ptr[node];
            int e1 = row_ptr[node + 1];
            if (staged) {
                const int* ep = eidx;
                gather_node(hv, l16, e0 - eb0, e1 - eb0,
                            [&](int e) { return ep[e]; }, acc);
            } else {
                gather_node(hv, l16, e0, e1,
                            [&](int e) { return edge_src[e]; }, acc);
            }
            float nd = norm_dst[node];
            #pragma unroll
            for (int p = 0; p < 8; ++p) acc[p] *= nd;
        }
        f16x8 o;
        #pragma unroll
        for (int p = 0; p < 8; ++p) o[p] = (_Float16)acc[p];
        Atile[nl * 16 + (l16 ^ (nl & 7))] = o;
    }
    __syncthreads();

    // ---- GEMM phase: 4 waves, each 16 rows x 128 cols ----
    int lane = tid & 63;
    int wave = tid >> 6;
    int m = lane & 15;
    int quad = lane >> 4;
    int rb = wave * 16;

    f32x4 acc[8] = {};
    #pragma unroll
    for (int kb = 0; kb < 4; ++kb) {
        int rl = rb + m;
        f16x8 a = Atile[rl * 16 + ((kb * 4 + quad) ^ (rl & 7))];
        const f16x8* wf = (const f16x8*)(Wf + (size_t)kb * 4096);
        #pragma unroll
        for (int nb = 0; nb < 8; ++nb) {
            f16x8 bfrag = wf[nb * 64 + lane];
            acc[nb] = __builtin_amdgcn_mfma_f32_16x16x32_f16(a, bfrag, acc[nb], 0, 0, 0);
        }
    }

    float bv[8];
    #pragma unroll
    for (int nb = 0; nb < 8; ++nb) bv[nb] = bias[nb * 16 + m];

    #pragma unroll
    for (int r = 0; r < 4; ++r) {
        int row = base + rb + quad * 4 + r;
        if (row < N) {
            if (out32 != nullptr) {
                #pragma unroll
                for (int nb = 0; nb < 8; ++nb)
                    out32[(size_t)row * 128 + nb * 16 + m] = acc[nb][r] + bv[nb];
            } else {
                float ns = norm_src[row];
                #pragma unroll
                for (int nb = 0; nb < 8; ++nb)
                    out16[(size_t)row * 128 + nb * 16 + m] =
                        __float2half((acc[nb][r] + bv[nb]) * ns);
            }
        }
    }
}

// ---------- launch ----------

extern "C" void kernel_launch(void* const* d_in, const int* in_sizes, int n_in,
                              void* d_out, int out_size, void* d_ws, size_t ws_size,
                              hipStream_t stream) {
    const float* feat = (const float*)d_in[0];
    const float* W    = (const float*)d_in[1];
    const float* b    = (const float*)d_in[2];
    const int*   src  = (const int*)d_in[3];
    const int*   dst  = (const int*)d_in[4];
    const int D = D_FEAT;
    const int N = in_sizes[0] / D;
    const int E = in_sizes[3];
    const int P = (N + 255) / 256;
    const int W4 = (N + 3) / 4;

    char* ws = (char*)d_ws;
    int* deg_in   = (int*)ws;                 // N
    int* row_ptr  = deg_in + N;               // N+1
    int* partials = row_ptr + (N + 1);        // P
    int* cursor   = partials + P;             // N (fallback only)
    int* edge_src = cursor + N;               // E
    float* norm_src_p = (float*)(edge_src + E);   // N
    float* norm_dst_p = norm_src_p + N;           // N
    unsigned char* rank = (unsigned char*)(norm_dst_p + N);  // E bytes
    unsigned* partialA = (unsigned*)(((size_t)(rank + E) + 255) & ~(size_t)255); // HB*W4
    unsigned* partialB = partialA + (size_t)HB * W4;                              // HB*W4
    size_t off = (size_t)((char*)(partialB + (size_t)HB * W4) - ws);
    off = (off + 255) & ~(size_t)255;
    __half* h_a = (__half*)(ws + off);            // N*128
    __half* h_b = h_a + (size_t)N * D;            // N*128
    _Float16* Wf = (_Float16*)(h_b + (size_t)N * D);  // 4*128*128

    bool fast = (2 * (size_t)W4 * 4 <= 160 * 1024 - 2048);
    if (fast) {
        hist_kernel<<<HB, 1024, 2 * (size_t)W4 * 4, stream>>>(
            src, dst, partialA, partialB, rank, E, W4);
        cumscan_kernel<<<(W4 + 63) / 64, 256, 0, stream>>>(
            partialA, partialB, W4, N, norm_src_p, norm_dst_p, deg_in, partials);
        scan_partials_kernel<<<1, 256, 0, stream>>>(partials, P, row_ptr, N, E);
        scan_final_kernel<<<P, 256, 0, stream>>>(deg_in, partials, row_ptr, cursor, N);
        bin2_kernel<<<HB, 1024, 0, stream>>>(src, dst, rank, row_ptr, partialB,
                                             edge_src, E, W4);
    } else {
        int* deg_out = (int*)partialA;
        hipMemsetAsync(deg_out, 0, sizeof(int) * (size_t)N, stream);
        hipMemsetAsync(deg_in, 0, sizeof(int) * (size_t)N, stream);
        degree_kernel<<<(E + 255) / 256, 256, 0, stream>>>(src, dst, deg_out, deg_in, E);
        norm_kernel<<<(N + 255) / 256, 256, 0, stream>>>(deg_out, deg_in, norm_src_p, norm_dst_p, N);
        scan_local_kernel<<<P, 256, 0, stream>>>(deg_in, row_ptr, partials, N);
        scan_partials_kernel<<<1, 256, 0, stream>>>(partials, P, row_ptr, N, E);
        scan_add_kernel<<<P, 256, 0, stream>>>(row_ptr, cursor, partials, N);
        bin_kernel<<<(E + 255) / 256, 256, 0, stream>>>(src, dst, cursor, edge_src, E);
    }
    int n4 = N * 32;
    int wtotal = N_LAYERS * 16384;
    conv_kernel<<<(n4 + wtotal + 255) / 256, 256, 0, stream>>>(
        feat, norm_src_p, h_a, W, Wf, n4, wtotal);

    const __half* hin = h_a;
    __half* hout = h_b;
    for (int l = 0; l < N_LAYERS; ++l) {
        bool last = (l == N_LAYERS - 1);
        agg_gemm_kernel<<<(N + 63) / 64, 256, 0, stream>>>(
            hin, row_ptr, edge_src, norm_dst_p,
            Wf + (size_t)l * 16384, b + (size_t)l * D, norm_src_p,
            last ? nullptr : hout, last ? (float*)d_out : nullptr, N);
        const __half* t = hin; hin = hout; hout = (__half*)t;
    }
}